// Round 2
// baseline (7854.586 us; speedup 1.0000x reference)
//
#include <hip/hip_runtime.h>

#define NN 100000
#define EE 640000
#define GG 256
#define LL 3
#define HH 128

constexpr int BM = 64;   // rows per block
constexpr int BK = 16;   // k-chunk

// ---------------------------------------------------------------------------
// Tiled fp32 GEMM: out[M,128] = X[M,K] @ W[K,128]
//   MODE 0: raw store
//   MODE 1: store relu(acc + bias)
//   MODE 3: split input: k<128 from X (=h), k>=128 from X2 (=agg) scaled by
//           inv[row]  (the MPNN update input [h | agg*inv]), K must be 256.
// 256 threads; thread tile 4 rows x 8 cols; BN = 128 (full width) so one
// block owns each 64-row stripe exclusively -> in-place X==out is safe.
// ---------------------------------------------------------------------------
template <int MODE>
__global__ __launch_bounds__(256) void gemm_k(
    const float* __restrict__ X, const float* __restrict__ W,
    const float* __restrict__ bias, float* __restrict__ out, int M, int K,
    const float* __restrict__ X2, const float* __restrict__ inv) {
  __shared__ __align__(16) float Xs[BK][BM];  // [k][m]
  __shared__ __align__(16) float Ws[BK][HH];

  const int tid = threadIdx.x;
  const int m0 = blockIdx.x * BM;
  const int tm = (tid >> 4) << 2;  // 0..60 step 4
  const int tn = (tid & 15) << 3;  // 0..120 step 8
  const int xr = tid >> 2;         // 0..63
  const int xc = (tid & 3) << 2;   // 0,4,8,12

  float acc[4][8];
#pragma unroll
  for (int i = 0; i < 4; ++i)
#pragma unroll
    for (int j = 0; j < 8; ++j) acc[i][j] = 0.f;

  for (int k0 = 0; k0 < K; k0 += BK) {
    float4 xv = make_float4(0.f, 0.f, 0.f, 0.f);
    if (m0 + xr < M) {
      if (MODE == 3) {
        if (k0 < HH) {
          xv = *(const float4*)(X + (size_t)(m0 + xr) * HH + k0 + xc);
        } else {
          xv = *(const float4*)(X2 + (size_t)(m0 + xr) * HH + (k0 - HH) + xc);
          const float s = inv[m0 + xr];
          xv.x *= s; xv.y *= s; xv.z *= s; xv.w *= s;
        }
      } else {
        xv = *(const float4*)(X + (size_t)(m0 + xr) * K + k0 + xc);
      }
    }
    Xs[xc + 0][xr] = xv.x;
    Xs[xc + 1][xr] = xv.y;
    Xs[xc + 2][xr] = xv.z;
    Xs[xc + 3][xr] = xv.w;
#pragma unroll
    for (int i = 0; i < 2; ++i) {
      const int q = tid + i * 256;
      const int row = q >> 5;
      const int c4 = (q & 31) << 2;
      *(float4*)&Ws[row][c4] =
          *(const float4*)(W + (size_t)(k0 + row) * HH + c4);
    }
    __syncthreads();
#pragma unroll
    for (int k = 0; k < BK; ++k) {
      const float4 x4 = *(const float4*)&Xs[k][tm];
      const float4 w0 = *(const float4*)&Ws[k][tn];
      const float4 w1 = *(const float4*)&Ws[k][tn + 4];
      const float xr_[4] = {x4.x, x4.y, x4.z, x4.w};
      const float wr_[8] = {w0.x, w0.y, w0.z, w0.w, w1.x, w1.y, w1.z, w1.w};
#pragma unroll
      for (int i = 0; i < 4; ++i)
#pragma unroll
        for (int j = 0; j < 8; ++j)
          acc[i][j] = fmaf(xr_[i], wr_[j], acc[i][j]);
    }
    __syncthreads();
  }

#pragma unroll
  for (int i = 0; i < 4; ++i) {
    const int r = m0 + tm + i;
    if (r >= M) continue;
    float o[8];
#pragma unroll
    for (int j = 0; j < 8; ++j) {
      float v = acc[i][j];
      if (MODE == 1 || MODE == 3) {
        v += bias[tn + j];
        v = v > 0.f ? v : 0.f;
      }
      o[j] = v;
    }
    float4* d4 = (float4*)(out + (size_t)r * HH + tn);
    d4[0] = make_float4(o[0], o[1], o[2], o[3]);
    d4[1] = make_float4(o[4], o[5], o[6], o[7]);
  }
}

// ---------------------------------------------------------------------------
// Fused message kernel for layer l (CHAIN = l):
//   per 64-edge block: t = relu(ea_tile @ We0 + be0)          [encoder]
//                      for j < CHAIN: t = relu(t @ We_j + be_j)  [edge chain]
//                      P = t @ WM_e                            [projection]
//   epilogue: v = relu(P + A[dst] + B[src] + bM); atomicAdd agg[dst] += v
// Never materializes edge hidden states in HBM.
// ---------------------------------------------------------------------------
template <int CHAIN>
__global__ __launch_bounds__(256) void msg_k(
    const float* __restrict__ ea, const float* __restrict__ We0,
    const float* __restrict__ be0, const float* __restrict__ WeL,
    const float* __restrict__ beL, const float* __restrict__ WMe,
    const float* __restrict__ bMl, const float* __restrict__ A,
    const float* __restrict__ B, const int* __restrict__ srcIdx,
    const int* __restrict__ dstIdx, float* __restrict__ agg) {
  __shared__ __align__(16) float T[HH][BM];    // t, [k][m] layout (32 KB)
  __shared__ __align__(16) float Ws[BK][HH];   // weight chunk (8 KB)
  __shared__ __align__(16) float EAs[16][BM];  // ea tile, [k][m] (4 KB)

  const int tid = threadIdx.x;
  const int r0 = blockIdx.x * BM;  // EE % 64 == 0, no guards needed
  const int tm = (tid >> 4) << 2;
  const int tn = (tid & 15) << 3;
  const int xr = tid >> 2;
  const int xc = (tid & 3) << 2;

  float acc[4][8];

  // ---- encoder: t0 = relu(ea @ We0 + be0) ----
  {
    const float4 v = *(const float4*)(ea + (size_t)(r0 + xr) * 16 + xc);
    EAs[xc + 0][xr] = v.x;
    EAs[xc + 1][xr] = v.y;
    EAs[xc + 2][xr] = v.z;
    EAs[xc + 3][xr] = v.w;
#pragma unroll
    for (int i = 0; i < 2; ++i) {
      const int q = tid + i * 256;
      const int row = q >> 5;
      const int c4 = (q & 31) << 2;
      *(float4*)&Ws[row][c4] = *(const float4*)(We0 + (size_t)row * HH + c4);
    }
  }
#pragma unroll
  for (int i = 0; i < 4; ++i)
#pragma unroll
    for (int j = 0; j < 8; ++j) acc[i][j] = 0.f;
  __syncthreads();
#pragma unroll
  for (int k = 0; k < 16; ++k) {
    const float4 x4 = *(const float4*)&EAs[k][tm];
    const float4 w0 = *(const float4*)&Ws[k][tn];
    const float4 w1 = *(const float4*)&Ws[k][tn + 4];
    const float xv[4] = {x4.x, x4.y, x4.z, x4.w};
    const float wv[8] = {w0.x, w0.y, w0.z, w0.w, w1.x, w1.y, w1.z, w1.w};
#pragma unroll
    for (int i = 0; i < 4; ++i)
#pragma unroll
      for (int j = 0; j < 8; ++j) acc[i][j] = fmaf(xv[i], wv[j], acc[i][j]);
  }
  __syncthreads();
  // write t0 -> T transposed: T[n][m]
#pragma unroll
  for (int j = 0; j < 8; ++j) {
    float4 c;
    c.x = fmaxf(acc[0][j] + be0[tn + j], 0.f);
    c.y = fmaxf(acc[1][j] + be0[tn + j], 0.f);
    c.z = fmaxf(acc[2][j] + be0[tn + j], 0.f);
    c.w = fmaxf(acc[3][j] + be0[tn + j], 0.f);
    *(float4*)&T[tn + j][tm] = c;
  }
  __syncthreads();

  // ---- chain steps: t = relu(t @ We_j + be_j) ----
#pragma unroll
  for (int step = 0; step < CHAIN; ++step) {
    const float* Wj = WeL + (size_t)step * HH * HH;
    const float* bj = beL + (size_t)step * HH;
#pragma unroll
    for (int i = 0; i < 4; ++i)
#pragma unroll
      for (int j = 0; j < 8; ++j) acc[i][j] = 0.f;
    for (int k0 = 0; k0 < HH; k0 += BK) {
#pragma unroll
      for (int i = 0; i < 2; ++i) {
        const int q = tid + i * 256;
        const int row = q >> 5;
        const int c4 = (q & 31) << 2;
        *(float4*)&Ws[row][c4] =
            *(const float4*)(Wj + (size_t)(k0 + row) * HH + c4);
      }
      __syncthreads();
#pragma unroll
      for (int k = 0; k < BK; ++k) {
        const float4 x4 = *(const float4*)&T[k0 + k][tm];
        const float4 w0 = *(const float4*)&Ws[k][tn];
        const float4 w1 = *(const float4*)&Ws[k][tn + 4];
        const float xv[4] = {x4.x, x4.y, x4.z, x4.w};
        const float wv[8] = {w0.x, w0.y, w0.z, w0.w, w1.x, w1.y, w1.z, w1.w};
#pragma unroll
        for (int i = 0; i < 4; ++i)
#pragma unroll
          for (int j = 0; j < 8; ++j)
            acc[i][j] = fmaf(xv[i], wv[j], acc[i][j]);
      }
      __syncthreads();
    }
    // overwrite T with relu(acc + bj) (all reads of old T are behind barrier)
#pragma unroll
    for (int j = 0; j < 8; ++j) {
      const float b = bj[tn + j];
      float4 c;
      c.x = fmaxf(acc[0][j] + b, 0.f);
      c.y = fmaxf(acc[1][j] + b, 0.f);
      c.z = fmaxf(acc[2][j] + b, 0.f);
      c.w = fmaxf(acc[3][j] + b, 0.f);
      *(float4*)&T[tn + j][tm] = c;
    }
    __syncthreads();
  }

  // ---- projection: P = t @ WM_e ----
#pragma unroll
  for (int i = 0; i < 4; ++i)
#pragma unroll
    for (int j = 0; j < 8; ++j) acc[i][j] = 0.f;
  for (int k0 = 0; k0 < HH; k0 += BK) {
#pragma unroll
    for (int i = 0; i < 2; ++i) {
      const int q = tid + i * 256;
      const int row = q >> 5;
      const int c4 = (q & 31) << 2;
      *(float4*)&Ws[row][c4] =
          *(const float4*)(WMe + (size_t)(k0 + row) * HH + c4);
    }
    __syncthreads();
#pragma unroll
    for (int k = 0; k < BK; ++k) {
      const float4 x4 = *(const float4*)&T[k0 + k][tm];
      const float4 w0 = *(const float4*)&Ws[k][tn];
      const float4 w1 = *(const float4*)&Ws[k][tn + 4];
      const float xv[4] = {x4.x, x4.y, x4.z, x4.w};
      const float wv[8] = {w0.x, w0.y, w0.z, w0.w, w1.x, w1.y, w1.z, w1.w};
#pragma unroll
      for (int i = 0; i < 4; ++i)
#pragma unroll
        for (int j = 0; j < 8; ++j) acc[i][j] = fmaf(xv[i], wv[j], acc[i][j]);
    }
    __syncthreads();
  }

  // ---- epilogue: gather A/B, relu, scatter-add ----
#pragma unroll
  for (int i = 0; i < 4; ++i) {
    const int r = r0 + tm + i;
    const int d = dstIdx[r];
    const int s = srcIdx[r];
    const float* Ar = A + (size_t)d * HH + tn;
    const float* Br = B + (size_t)s * HH + tn;
    float* Or = agg + (size_t)d * HH + tn;
#pragma unroll
    for (int j = 0; j < 8; ++j) {
      float v = acc[i][j] + Ar[j] + Br[j] + bMl[tn + j];
      v = v > 0.f ? v : 0.f;
      atomicAdd(&Or[j], v);
    }
  }
}

// ---------------------------------------------------------------------------
__global__ void count_kernel(const int* __restrict__ dst, int* cnt, int E) {
  const int i = blockIdx.x * 256 + threadIdx.x;
  if (i < E) atomicAdd(&cnt[dst[i]], 1);
}

__global__ void invcnt_kernel(const int* __restrict__ cnt, float* inv, int n) {
  const int i = blockIdx.x * 256 + threadIdx.x;
  if (i < n) inv[i] = 1.0f / (float)max(cnt[i], 1);
}

__global__ void pool_accum(const float* __restrict__ h,
                           const int* __restrict__ batch,
                           float* __restrict__ gsum, int M) {
  const int col = threadIdx.x;  // 0..127
  const int r0 = blockIdx.x * 64;
  const int rend = min(r0 + 64, M);
  if (r0 >= M) return;
  float acc = 0.f;
  int cur = batch[r0];
  for (int r = r0; r < rend; ++r) {
    const int b = batch[r];
    if (b != cur) {
      atomicAdd(&gsum[(size_t)cur * HH + col], acc);
      acc = 0.f;
      cur = b;
    }
    acc += h[(size_t)r * HH + col];
  }
  atomicAdd(&gsum[(size_t)cur * HH + col], acc);
}

__global__ void gcnt_kernel(const int* __restrict__ batch, int* gcnt, int n) {
  const int i = blockIdx.x * 256 + threadIdx.x;
  if (i < n) atomicAdd(&gcnt[batch[i]], 1);
}

__global__ void head_kernel(const float* __restrict__ gsum,
                            const int* __restrict__ gcnt,
                            const float* __restrict__ Wh,
                            const float* __restrict__ bh,
                            float* __restrict__ out) {
  const int g = blockIdx.x;
  const int t = threadIdx.x;  // 128 threads
  float v = gsum[(size_t)g * HH + t] * Wh[t];
#pragma unroll
  for (int o = 32; o > 0; o >>= 1) v += __shfl_down(v, o, 64);
  __shared__ float red[2];
  if ((t & 63) == 0) red[t >> 6] = v;
  __syncthreads();
  if (t == 0) {
    const float s = red[0] + red[1];
    const float c = (float)max(gcnt[g], 1);
    out[g] = s / c + bh[0];
  }
}

// ---------------------------------------------------------------------------
extern "C" void kernel_launch(void* const* d_in, const int* in_sizes, int n_in,
                              void* d_out, int out_size, void* d_ws,
                              size_t ws_size, hipStream_t stream) {
  (void)in_sizes; (void)n_in; (void)out_size;
  const float* x = (const float*)d_in[0];
  const int* ei = (const int*)d_in[1];
  const float* ea = (const float*)d_in[2];
  const int* batch = (const int*)d_in[3];
  const float* Wn0 = (const float*)d_in[4];
  const float* bn0 = (const float*)d_in[5];
  const float* We0 = (const float*)d_in[6];
  const float* be0 = (const float*)d_in[7];
  const float* WM = (const float*)d_in[8];
  const float* bM = (const float*)d_in[9];
  const float* WU = (const float*)d_in[10];
  const float* bU = (const float*)d_in[11];
  const float* Wn = (const float*)d_in[12];
  const float* bn = (const float*)d_in[13];
  const float* We = (const float*)d_in[14];
  const float* be = (const float*)d_in[15];
  const float* Wh = (const float*)d_in[16];
  const float* bh = (const float*)d_in[17];

  const int* srcI = ei;       // edge_index[0]
  const int* dstI = ei + EE;  // edge_index[1]

  // workspace carve (floats) — total ~51.4M floats ≈ 206 MB
  float* w = (float*)d_ws;
  size_t o = 0;
  float* h = w + o;    o += (size_t)NN * HH;
  float* A = w + o;    o += (size_t)NN * HH;
  float* B = w + o;    o += (size_t)NN * HH;
  float* agg = w + o;  o += (size_t)NN * HH;
  float* gsum = w + o; o += (size_t)GG * HH;
  float* invc = w + o; o += (size_t)NN;
  int* cnt = (int*)(w + o);  o += (size_t)NN;
  int* gcnt = (int*)(w + o); o += (size_t)GG;
  if (o * sizeof(float) > ws_size) return;  // clean diagnosable failure

  const dim3 blk(256);
  const int gridN = (NN + BM - 1) / BM;  // 1563
  const int gridE = EE / BM;             // 10000

  hipMemsetAsync(cnt, 0, (size_t)NN * sizeof(int), stream);
  hipMemsetAsync(gsum, 0, (size_t)GG * HH * sizeof(float), stream);
  hipMemsetAsync(gcnt, 0, (size_t)GG * sizeof(int), stream);

  count_kernel<<<(EE + 255) / 256, blk, 0, stream>>>(dstI, cnt, EE);
  invcnt_kernel<<<(NN + 255) / 256, blk, 0, stream>>>(cnt, invc, NN);

  // node encoder: h = relu(x @ Wn0 + bn0)
  gemm_k<1><<<gridN, blk, 0, stream>>>(x, Wn0, bn0, h, NN, 64, nullptr,
                                       nullptr);

  for (int l = 0; l < LL; ++l) {
    const float* WMl = WM + (size_t)l * 3 * HH * HH;
    // A = h @ WM_dst, B = h @ WM_src  (node-side message halves)
    gemm_k<0><<<gridN, blk, 0, stream>>>(h, WMl, nullptr, A, NN, HH, nullptr,
                                         nullptr);
    gemm_k<0><<<gridN, blk, 0, stream>>>(h, WMl + HH * HH, nullptr, B, NN, HH,
                                         nullptr, nullptr);
    hipMemsetAsync(agg, 0, (size_t)NN * HH * sizeof(float), stream);
    // fused edge chain + projection + scatter
    switch (l) {
      case 0:
        msg_k<0><<<gridE, blk, 0, stream>>>(ea, We0, be0, We, be,
                                            WMl + 2 * HH * HH, bM + l * HH, A,
                                            B, srcI, dstI, agg);
        break;
      case 1:
        msg_k<1><<<gridE, blk, 0, stream>>>(ea, We0, be0, We, be,
                                            WMl + 2 * HH * HH, bM + l * HH, A,
                                            B, srcI, dstI, agg);
        break;
      default:
        msg_k<2><<<gridE, blk, 0, stream>>>(ea, We0, be0, We, be,
                                            WMl + 2 * HH * HH, bM + l * HH, A,
                                            B, srcI, dstI, agg);
        break;
    }
    // h = relu([h | agg*inv] @ WU + bU)  (in-place safe)
    gemm_k<3><<<gridN, blk, 0, stream>>>(h, WU + (size_t)l * 2 * HH * HH,
                                         bU + l * HH, h, NN, 2 * HH, agg,
                                         invc);
    // h = relu(h @ Wn + bn)  (in-place safe)
    gemm_k<1><<<gridN, blk, 0, stream>>>(h, Wn + (size_t)l * HH * HH,
                                         bn + l * HH, h, NN, HH, nullptr,
                                         nullptr);
  }

  pool_accum<<<gridN, dim3(128), 0, stream>>>(h, batch, gsum, NN);
  gcnt_kernel<<<(NN + 255) / 256, blk, 0, stream>>>(batch, gcnt, NN);
  head_kernel<<<GG, dim3(128), 0, stream>>>(gsum, gcnt, Wh, bh, (float*)d_out);
}

// Round 4
// 2897.252 us; speedup vs baseline: 2.7110x; 2.7110x over previous
//
#include <hip/hip_runtime.h>

#define NN 100000
#define EE 640000
#define GG 256
#define LL 3
#define HH 128

constexpr int BM = 64;   // rows per block
constexpr int BK = 16;   // k-chunk

// ---------------------------------------------------------------------------
// Tiled fp32 GEMM: out[M,128] = X[M,K] @ W[K,128]
//   MODE 0: raw store
//   MODE 1: store relu(acc + bias)
//   MODE 3: split input: k<128 from X (=h), k>=128 from X2 (=agg) * inv[row]
// ---------------------------------------------------------------------------
template <int MODE>
__global__ __launch_bounds__(256) void gemm_k(
    const float* __restrict__ X, const float* __restrict__ W,
    const float* __restrict__ bias, float* __restrict__ out, int M, int K,
    const float* __restrict__ X2, const float* __restrict__ inv) {
  __shared__ __align__(16) float Xs[BK][BM];
  __shared__ __align__(16) float Ws[BK][HH];

  const int tid = threadIdx.x;
  const int m0 = blockIdx.x * BM;
  const int tm = (tid >> 4) << 2;
  const int tn = (tid & 15) << 3;
  const int xr = tid >> 2;
  const int xc = (tid & 3) << 2;

  float acc[4][8];
#pragma unroll
  for (int i = 0; i < 4; ++i)
#pragma unroll
    for (int j = 0; j < 8; ++j) acc[i][j] = 0.f;

  for (int k0 = 0; k0 < K; k0 += BK) {
    float4 xv = make_float4(0.f, 0.f, 0.f, 0.f);
    if (m0 + xr < M) {
      if (MODE == 3) {
        if (k0 < HH) {
          xv = *(const float4*)(X + (size_t)(m0 + xr) * HH + k0 + xc);
        } else {
          xv = *(const float4*)(X2 + (size_t)(m0 + xr) * HH + (k0 - HH) + xc);
          const float s = inv[m0 + xr];
          xv.x *= s; xv.y *= s; xv.z *= s; xv.w *= s;
        }
      } else {
        xv = *(const float4*)(X + (size_t)(m0 + xr) * K + k0 + xc);
      }
    }
    Xs[xc + 0][xr] = xv.x;
    Xs[xc + 1][xr] = xv.y;
    Xs[xc + 2][xr] = xv.z;
    Xs[xc + 3][xr] = xv.w;
#pragma unroll
    for (int i = 0; i < 2; ++i) {
      const int q = tid + i * 256;
      const int row = q >> 5;
      const int c4 = (q & 31) << 2;
      *(float4*)&Ws[row][c4] =
          *(const float4*)(W + (size_t)(k0 + row) * HH + c4);
    }
    __syncthreads();
#pragma unroll
    for (int k = 0; k < BK; ++k) {
      const float4 x4 = *(const float4*)&Xs[k][tm];
      const float4 w0 = *(const float4*)&Ws[k][tn];
      const float4 w1 = *(const float4*)&Ws[k][tn + 4];
      const float xr_[4] = {x4.x, x4.y, x4.z, x4.w};
      const float wr_[8] = {w0.x, w0.y, w0.z, w0.w, w1.x, w1.y, w1.z, w1.w};
#pragma unroll
      for (int i = 0; i < 4; ++i)
#pragma unroll
        for (int j = 0; j < 8; ++j)
          acc[i][j] = fmaf(xr_[i], wr_[j], acc[i][j]);
    }
    __syncthreads();
  }

#pragma unroll
  for (int i = 0; i < 4; ++i) {
    const int r = m0 + tm + i;
    if (r >= M) continue;
    float o[8];
#pragma unroll
    for (int j = 0; j < 8; ++j) {
      float v = acc[i][j];
      if (MODE == 1 || MODE == 3) {
        v += bias[tn + j];
        v = v > 0.f ? v : 0.f;
      }
      o[j] = v;
    }
    float4* d4 = (float4*)(out + (size_t)r * HH + tn);
    d4[0] = make_float4(o[0], o[1], o[2], o[3]);
    d4[1] = make_float4(o[4], o[5], o[6], o[7]);
  }
}

// ---------------------------------------------------------------------------
// Fused message kernel, edges pre-sorted by dst.
//   t = relu(ea@We0+be0); CHAIN x (t = relu(t@We_j+be_j)); P = t@WMe
//   v = relu(P + A[dst] + B[src] + bM)  -> LDS -> segmented run reduction
//   -> one atomicAdd per (run, col) into agg.
// W chunks software-pipelined: prefetch next chunk (2 x float4 per thread =
// full 16x128 chunk), double-buffered LDS, ONE barrier per chunk.
// ---------------------------------------------------------------------------
template <int CHAIN>
__global__ __launch_bounds__(256) void msg_k(
    const float* __restrict__ ea, const float* __restrict__ We0,
    const float* __restrict__ be0, const float* __restrict__ WeL,
    const float* __restrict__ beL, const float* __restrict__ WMe,
    const float* __restrict__ bMl, const float* __restrict__ A,
    const float* __restrict__ B, const int* __restrict__ sIdx,
    const int* __restrict__ sSrc, const int* __restrict__ sDst,
    float* __restrict__ agg) {
  // TV: chain layout T[k][m] = TV[k*64+m] (k<128); epilogue V[e][c] = TV[e*129+c]
  __shared__ __align__(16) float TV[64 * 129];
  __shared__ __align__(16) float Wb[2][BK * HH];  // double-buffered W chunk
  __shared__ int dstS[64];

  const int tid = threadIdx.x;
  const int r0 = blockIdx.x * BM;  // EE % 64 == 0
  const int tm = (tid >> 4) << 2;
  const int tn = (tid & 15) << 3;
  const int xr = tid >> 2;
  const int xc = (tid & 3) << 2;

  const int NC = 1 + 8 * CHAIN + 8;  // total W chunks

  auto cptr = [&](int t) -> const float* {
    if (t == 0) return We0;
    t -= 1;
    if (t < 8 * CHAIN)
      return WeL + (size_t)(t >> 3) * HH * HH + (t & 7) * BK * HH;
    t -= 8 * CHAIN;
    return WMe + (size_t)t * BK * HH;
  };

  // stage EA tile into TV rows 0..15 (dead T rows) + dst values
  {
    const int e = sIdx[r0 + xr];
    const float4 v = *(const float4*)(ea + (size_t)e * 16 + xc);
    TV[(xc + 0) * 64 + xr] = v.x;
    TV[(xc + 1) * 64 + xr] = v.y;
    TV[(xc + 2) * 64 + xr] = v.z;
    TV[(xc + 3) * 64 + xr] = v.w;
    if (tid < 64) dstS[tid] = sDst[r0 + tid];
  }

  float acc[4][8];
#pragma unroll
  for (int i = 0; i < 4; ++i)
#pragma unroll
    for (int j = 0; j < 8; ++j) acc[i][j] = 0.f;

  // full chunk = 512 float4; 256 threads stage 2 float4 each
  float4 wreg0 = ((const float4*)cptr(0))[tid];
  float4 wreg1 = ((const float4*)cptr(0))[tid + 256];
  int t = 0;

  auto do_chunk = [&](int krow0) {
    float4 wn0 = wreg0, wn1 = wreg1;
    if (t + 1 < NC) {
      wn0 = ((const float4*)cptr(t + 1))[tid];
      wn1 = ((const float4*)cptr(t + 1))[tid + 256];
    }
    ((float4*)&Wb[t & 1][0])[tid] = wreg0;
    ((float4*)&Wb[t & 1][0])[tid + 256] = wreg1;
    __syncthreads();
    const float* wsb = &Wb[t & 1][0];
#pragma unroll
    for (int k = 0; k < BK; ++k) {
      const float4 x4 = *(const float4*)&TV[(krow0 + k) * 64 + tm];
      const float4 w0 = *(const float4*)&wsb[k * HH + tn];
      const float4 w1 = *(const float4*)&wsb[k * HH + tn + 4];
      const float xv[4] = {x4.x, x4.y, x4.z, x4.w};
      const float wv[8] = {w0.x, w0.y, w0.z, w0.w, w1.x, w1.y, w1.z, w1.w};
#pragma unroll
      for (int i = 0; i < 4; ++i)
#pragma unroll
        for (int j = 0; j < 8; ++j) acc[i][j] = fmaf(xv[i], wv[j], acc[i][j]);
    }
    wreg0 = wn0;
    wreg1 = wn1;
    ++t;
  };

  auto writeback_relu = [&](const float* bias) {
    __syncthreads();  // all TV reads of this phase done
#pragma unroll
    for (int j = 0; j < 8; ++j) {
      const float b = bias[tn + j];
      float4 c;
      c.x = fmaxf(acc[0][j] + b, 0.f);
      c.y = fmaxf(acc[1][j] + b, 0.f);
      c.z = fmaxf(acc[2][j] + b, 0.f);
      c.w = fmaxf(acc[3][j] + b, 0.f);
      *(float4*)&TV[(tn + j) * 64 + tm] = c;
    }
#pragma unroll
    for (int i = 0; i < 4; ++i)
#pragma unroll
      for (int j = 0; j < 8; ++j) acc[i][j] = 0.f;
    // next do_chunk's barrier orders these writes before reads
  };

  // encoder (1 chunk, reads EA rows 0..15)
  do_chunk(0);
  writeback_relu(be0);
  // chain steps
#pragma unroll
  for (int s = 0; s < CHAIN; ++s) {
#pragma unroll
    for (int kc = 0; kc < 8; ++kc) do_chunk(kc * BK);
    writeback_relu(beL + (size_t)s * HH);
  }
  // projection
#pragma unroll
  for (int kc = 0; kc < 8; ++kc) do_chunk(kc * BK);

  // epilogue: v = relu(P + A[dst] + B[src] + bM) -> V (stride 129)
  __syncthreads();  // TV chain reads done; reuse as V
  const float4 m0v = *(const float4*)(bMl + tn);
  const float4 m1v = *(const float4*)(bMl + tn + 4);
#pragma unroll
  for (int i = 0; i < 4; ++i) {
    const int rr = r0 + tm + i;
    const int d = dstS[tm + i];
    const int s = sSrc[rr];
    const float4 a0 = *(const float4*)(A + (size_t)d * HH + tn);
    const float4 a1 = *(const float4*)(A + (size_t)d * HH + tn + 4);
    const float4 b0 = *(const float4*)(B + (size_t)s * HH + tn);
    const float4 b1 = *(const float4*)(B + (size_t)s * HH + tn + 4);
    float* vp = &TV[(tm + i) * 129 + tn];
    vp[0] = fmaxf(acc[i][0] + a0.x + b0.x + m0v.x, 0.f);
    vp[1] = fmaxf(acc[i][1] + a0.y + b0.y + m0v.y, 0.f);
    vp[2] = fmaxf(acc[i][2] + a0.z + b0.z + m0v.z, 0.f);
    vp[3] = fmaxf(acc[i][3] + a0.w + b0.w + m0v.w, 0.f);
    vp[4] = fmaxf(acc[i][4] + a1.x + b1.x + m1v.x, 0.f);
    vp[5] = fmaxf(acc[i][5] + a1.y + b1.y + m1v.y, 0.f);
    vp[6] = fmaxf(acc[i][6] + a1.z + b1.z + m1v.z, 0.f);
    vp[7] = fmaxf(acc[i][7] + a1.w + b1.w + m1v.w, 0.f);
  }
  __syncthreads();

  // segmented run reduction: wave-uniform strips (c = tid&127, h = tid>>7)
  const int c = tid & 127;
  const int h = tid >> 7;  // waves 0-1: edges 0..31, waves 2-3: edges 32..63
  float racc = 0.f;
  int cur = dstS[h * 32];
  for (int e2 = h * 32; e2 < h * 32 + 32; ++e2) {
    const int d = dstS[e2];
    if (d != cur) {
      atomicAdd(&agg[(size_t)cur * HH + c], racc);
      racc = 0.f;
      cur = d;
    }
    racc += TV[e2 * 129 + c];
  }
  atomicAdd(&agg[(size_t)cur * HH + c], racc);
}

// ---------------------------------------------------------------------------
__global__ void count_kernel(const int* __restrict__ dst, int* cnt, int E) {
  const int i = blockIdx.x * 256 + threadIdx.x;
  if (i < E) atomicAdd(&cnt[dst[i]], 1);
}

__global__ void invcnt_kernel(const int* __restrict__ cnt, float* inv, int n) {
  const int i = blockIdx.x * 256 + threadIdx.x;
  if (i < n) inv[i] = 1.0f / (float)max(cnt[i], 1);
}

__global__ void scan_block(const int* __restrict__ cnt, int* excl, int* bsum,
                           int n) {
  __shared__ int s[256];
  const int tx = threadIdx.x;
  const int i = blockIdx.x * 256 + tx;
  const int v = (i < n) ? cnt[i] : 0;
  s[tx] = v;
  __syncthreads();
  for (int off = 1; off < 256; off <<= 1) {
    int tv = (tx >= off) ? s[tx - off] : 0;
    __syncthreads();
    s[tx] += tv;
    __syncthreads();
  }
  if (i < n) excl[i] = s[tx] - v;
  if (tx == 255) bsum[blockIdx.x] = s[255];
}

__global__ void scan_bsum(int* bsum, int nb) {
  if (threadIdx.x == 0 && blockIdx.x == 0) {
    int acc = 0;
    for (int i = 0; i < nb; ++i) {
      const int t = bsum[i];
      bsum[i] = acc;
      acc += t;
    }
  }
}

__global__ void scan_add(int* excl, const int* __restrict__ bsum, int n) {
  const int i = blockIdx.x * 256 + threadIdx.x;
  if (i < n) excl[i] += bsum[blockIdx.x];
}

__global__ void scatter_edges(const int* __restrict__ dst,
                              const int* __restrict__ src,
                              const int* __restrict__ off, int* ctr, int* sIdx,
                              int* sSrc, int* sDst, int E) {
  const int e = blockIdx.x * 256 + threadIdx.x;
  if (e >= E) return;
  const int d = dst[e];
  const int p = off[d] + atomicAdd(&ctr[d], 1);
  sIdx[p] = e;
  sSrc[p] = src[e];
  sDst[p] = d;
}

__global__ void pool_accum(const float* __restrict__ h,
                           const int* __restrict__ batch,
                           float* __restrict__ gsum, int M) {
  const int col = threadIdx.x;
  const int r0 = blockIdx.x * 64;
  const int rend = min(r0 + 64, M);
  if (r0 >= M) return;
  float acc = 0.f;
  int cur = batch[r0];
  for (int r = r0; r < rend; ++r) {
    const int b = batch[r];
    if (b != cur) {
      atomicAdd(&gsum[(size_t)cur * HH + col], acc);
      acc = 0.f;
      cur = b;
    }
    acc += h[(size_t)r * HH + col];
  }
  atomicAdd(&gsum[(size_t)cur * HH + col], acc);
}

__global__ void gcnt_kernel(const int* __restrict__ batch, int* gcnt, int n) {
  const int i = blockIdx.x * 256 + threadIdx.x;
  if (i < n) atomicAdd(&gcnt[batch[i]], 1);
}

__global__ void head_kernel(const float* __restrict__ gsum,
                            const int* __restrict__ gcnt,
                            const float* __restrict__ Wh,
                            const float* __restrict__ bh,
                            float* __restrict__ out) {
  const int g = blockIdx.x;
  const int t = threadIdx.x;  // 128 threads
  float v = gsum[(size_t)g * HH + t] * Wh[t];
#pragma unroll
  for (int o = 32; o > 0; o >>= 1) v += __shfl_down(v, o, 64);
  __shared__ float red[2];
  if ((t & 63) == 0) red[t >> 6] = v;
  __syncthreads();
  if (t == 0) {
    const float s = red[0] + red[1];
    const float c = (float)max(gcnt[g], 1);
    out[g] = s / c + bh[0];
  }
}

// ---------------------------------------------------------------------------
extern "C" void kernel_launch(void* const* d_in, const int* in_sizes, int n_in,
                              void* d_out, int out_size, void* d_ws,
                              size_t ws_size, hipStream_t stream) {
  (void)in_sizes; (void)n_in; (void)out_size;
  const float* x = (const float*)d_in[0];
  const int* ei = (const int*)d_in[1];
  const float* ea = (const float*)d_in[2];
  const int* batch = (const int*)d_in[3];
  const float* Wn0 = (const float*)d_in[4];
  const float* bn0 = (const float*)d_in[5];
  const float* We0 = (const float*)d_in[6];
  const float* be0 = (const float*)d_in[7];
  const float* WM = (const float*)d_in[8];
  const float* bM = (const float*)d_in[9];
  const float* WU = (const float*)d_in[10];
  const float* bU = (const float*)d_in[11];
  const float* Wn = (const float*)d_in[12];
  const float* bn = (const float*)d_in[13];
  const float* We = (const float*)d_in[14];
  const float* be = (const float*)d_in[15];
  const float* Wh = (const float*)d_in[16];
  const float* bh = (const float*)d_in[17];

  const int* srcI = ei;       // edge_index[0]
  const int* dstI = ei + EE;  // edge_index[1]

  // workspace carve (floats/ints) — ~214 MB
  float* w = (float*)d_ws;
  size_t o = 0;
  float* h = w + o;    o += (size_t)NN * HH;
  float* A = w + o;    o += (size_t)NN * HH;
  float* B = w + o;    o += (size_t)NN * HH;
  float* agg = w + o;  o += (size_t)NN * HH;
  float* gsum = w + o; o += (size_t)GG * HH;
  float* invc = w + o; o += (size_t)NN;
  int* cnt = (int*)(w + o);  o += (size_t)NN;
  int* gcnt = (int*)(w + o); o += (size_t)GG;
  int* off = (int*)(w + o);  o += (size_t)NN;
  int* ctr = (int*)(w + o);  o += (size_t)NN;
  int* bsum = (int*)(w + o); o += 512;
  int* sIdx = (int*)(w + o); o += (size_t)EE;
  int* sSrc = (int*)(w + o); o += (size_t)EE;
  int* sDst = (int*)(w + o); o += (size_t)EE;
  if (o * sizeof(float) > ws_size) return;  // clean diagnosable failure

  const dim3 blk(256);
  const int gridN = (NN + BM - 1) / BM;   // 1563
  const int gridE = EE / BM;              // 10000
  const int NBLK = (NN + 255) / 256;      // 391

  hipMemsetAsync(cnt, 0, (size_t)NN * sizeof(int), stream);
  hipMemsetAsync(ctr, 0, (size_t)NN * sizeof(int), stream);
  hipMemsetAsync(gsum, 0, (size_t)GG * HH * sizeof(float), stream);
  hipMemsetAsync(gcnt, 0, (size_t)GG * sizeof(int), stream);

  count_kernel<<<(EE + 255) / 256, blk, 0, stream>>>(dstI, cnt, EE);
  scan_block<<<NBLK, blk, 0, stream>>>(cnt, off, bsum, NN);
  scan_bsum<<<1, 1, 0, stream>>>(bsum, NBLK);
  scan_add<<<NBLK, blk, 0, stream>>>(off, bsum, NN);
  scatter_edges<<<(EE + 255) / 256, blk, 0, stream>>>(dstI, srcI, off, ctr,
                                                      sIdx, sSrc, sDst, EE);
  invcnt_kernel<<<(NN + 255) / 256, blk, 0, stream>>>(cnt, invc, NN);

  // node encoder: h = relu(x @ Wn0 + bn0)
  gemm_k<1><<<gridN, blk, 0, stream>>>(x, Wn0, bn0, h, NN, 64, nullptr,
                                       nullptr);

  for (int l = 0; l < LL; ++l) {
    const float* WMl = WM + (size_t)l * 3 * HH * HH;
    gemm_k<0><<<gridN, blk, 0, stream>>>(h, WMl, nullptr, A, NN, HH, nullptr,
                                         nullptr);
    gemm_k<0><<<gridN, blk, 0, stream>>>(h, WMl + HH * HH, nullptr, B, NN, HH,
                                         nullptr, nullptr);
    hipMemsetAsync(agg, 0, (size_t)NN * HH * sizeof(float), stream);
    switch (l) {
      case 0:
        msg_k<0><<<gridE, blk, 0, stream>>>(ea, We0, be0, We, be,
                                            WMl + 2 * HH * HH, bM + l * HH, A,
                                            B, sIdx, sSrc, sDst, agg);
        break;
      case 1:
        msg_k<1><<<gridE, blk, 0, stream>>>(ea, We0, be0, We, be,
                                            WMl + 2 * HH * HH, bM + l * HH, A,
                                            B, sIdx, sSrc, sDst, agg);
        break;
      default:
        msg_k<2><<<gridE, blk, 0, stream>>>(ea, We0, be0, We, be,
                                            WMl + 2 * HH * HH, bM + l * HH, A,
                                            B, sIdx, sSrc, sDst, agg);
        break;
    }
    gemm_k<3><<<gridN, blk, 0, stream>>>(h, WU + (size_t)l * 2 * HH * HH,
                                         bU + l * HH, h, NN, 2 * HH, agg,
                                         invc);
    gemm_k<1><<<gridN, blk, 0, stream>>>(h, Wn + (size_t)l * HH * HH,
                                         bn + l * HH, h, NN, HH, nullptr,
                                         nullptr);
  }

  pool_accum<<<gridN, dim3(128), 0, stream>>>(h, batch, gsum, NN);
  gcnt_kernel<<<(NN + 255) / 256, blk, 0, stream>>>(batch, gcnt, NN);
  head_kernel<<<GG, dim3(128), 0, stream>>>(gsum, gcnt, Wh, bh, (float*)d_out);
}